// Round 6
// baseline (28.222 us; speedup 1.0000x reference)
//
#include <hip/hip_runtime.h>
#include <hip/hip_bf16.h>

// Problem constants (from the reference)
constexpr int B = 16, C = 2, H = 512, W = 512;
constexpr int HW = H * W;                    // 262144 pixels per batch
constexpr int BLOCKS_PER_BATCH = 128;        // 2048 pixels per block
constexpr int NBLK = B * BLOCKS_PER_BATCH;   // 2048 blocks
constexpr int THREADS = 512;                 // 4 pixels per thread (1 x float4 per array)
constexpr float BG_WEIGHT = 0.4f;

// Workspace layout (floats):
//   ws[0      .. NBLK)    per-block entropy partial
//   ws[NBLK   .. 2*NBLK)  per-block fg squared-error partial
//   ws[2*NBLK .. 3*NBLK)  per-block fg count partial
// Every slot is unconditionally written each launch -> no zeroing needed.
__global__ __launch_bounds__(THREADS) void coloss_reduce(
    const float* __restrict__ conf,   // [B,2,H,W]
    const float* __restrict__ off,    // [B,2,H,W]
    const int*   __restrict__ inst,   // [B,1,H,W]
    const float* __restrict__ gto,    // [B,2,H,W]
    float* __restrict__ ws)
{
    const int b   = blockIdx.x / BLOCKS_PER_BATCH;
    const int blk = blockIdx.x % BLOCKS_PER_BATCH;

    const float* conf0 = conf + (size_t)b * C * HW;
    const float* conf1 = conf0 + HW;
    const float* off0  = off  + (size_t)b * 2 * HW;
    const float* off1  = off0 + HW;
    const float* gt0   = gto  + (size_t)b * 2 * HW;
    const float* gt1   = gt0 + HW;
    const int*   ins   = inst + (size_t)b * HW;

    // one float4 group per thread: 512 threads x 4 px = 2048 px per block
    const int p = blk * THREADS + (int)threadIdx.x;

    // issue all 7 loads before any compute
    const float4 c0 = ((const float4*)conf0)[p];
    const float4 c1 = ((const float4*)conf1)[p];
    const float4 o0 = ((const float4*)off0)[p];
    const float4 o1 = ((const float4*)off1)[p];
    const float4 g0 = ((const float4*)gt0)[p];
    const float4 g1 = ((const float4*)gt1)[p];
    const int4   iv = ((const int4*)ins)[p];

    float entAcc = 0.f;
    float sqAcc  = 0.f;
    float fcnt   = 0.f;

    auto accum = [&](float cc0, float cc1, float oo0, float oo1,
                     float gg0, float gg1, int ii) {
        const bool fg = (ii != 0);
        const float gathered = fg ? cc1 : cc0;
        float e = -__logf(gathered);
        e *= fg ? 1.0f : BG_WEIGHT;
        entAcc += e;
        const float d0 = gg0 - oo0;
        const float d1 = gg1 - oo1;
        const float t  = d0 * d0 + d1 * d1;
        if (fg) { sqAcc += t; fcnt += 1.0f; }
    };

    accum(c0.x, c1.x, o0.x, o1.x, g0.x, g1.x, iv.x);
    accum(c0.y, c1.y, o0.y, o1.y, g0.y, g1.y, iv.y);
    accum(c0.z, c1.z, o0.z, o1.z, g0.z, g1.z, iv.z);
    accum(c0.w, c1.w, o0.w, o1.w, g0.w, g1.w, iv.w);

    // wave (64-lane) butterfly reduce
    #pragma unroll
    for (int m = 32; m >= 1; m >>= 1) {
        entAcc += __shfl_xor(entAcc, m, 64);
        sqAcc  += __shfl_xor(sqAcc,  m, 64);
        fcnt   += __shfl_xor(fcnt,   m, 64);
    }

    __shared__ float sEnt[8], sSq[8], sCnt[8];
    const int wave = threadIdx.x >> 6;
    const int lane = threadIdx.x & 63;
    if (lane == 0) { sEnt[wave] = entAcc; sSq[wave] = sqAcc; sCnt[wave] = fcnt; }
    __syncthreads();

    if (threadIdx.x == 0) {
        float e = 0.f, s = 0.f, c = 0.f;
        #pragma unroll
        for (int w = 0; w < 8; ++w) { e += sEnt[w]; s += sSq[w]; c += sCnt[w]; }
        const int g = blockIdx.x;
        ws[g]            = e;
        ws[NBLK + g]     = s;
        ws[2 * NBLK + g] = c;
    }
}

__global__ __launch_bounds__(256) void coloss_finalize(const float* __restrict__ ws,
                                                       float* __restrict__ out)
{
    const float* entp = ws;
    const float* sqp  = ws + NBLK;
    const float* cntp = ws + 2 * NBLK;

    // --- entropy: sum all NBLK partials across the block ---
    float e = 0.f;
    for (int i = threadIdx.x; i < NBLK; i += 256) e += entp[i];

    // --- per-batch sq/cnt: 16 threads per batch, 8 entries each ---
    const int b = threadIdx.x >> 4;       // 0..15
    const int t = threadIdx.x & 15;       // 0..15
    float s = 0.f, c = 0.f;
    for (int i = t; i < BLOCKS_PER_BATCH; i += 16) {
        s += sqp[b * BLOCKS_PER_BATCH + i];
        c += cntp[b * BLOCKS_PER_BATCH + i];
    }
    #pragma unroll
    for (int m = 8; m >= 1; m >>= 1) {    // reduce within 16-lane subgroup
        s += __shfl_xor(s, m, 64);
        c += __shfl_xor(c, m, 64);
    }
    __shared__ float sRatio[16];
    if (t == 0) sRatio[b] = (c > 0.f) ? (s / c) : 0.f;

    // entropy wave reduce + cross-wave via LDS
    #pragma unroll
    for (int m = 32; m >= 1; m >>= 1) e += __shfl_xor(e, m, 64);
    __shared__ float sE[4];
    if ((threadIdx.x & 63) == 0) sE[threadIdx.x >> 6] = e;
    __syncthreads();

    if (threadIdx.x == 0) {
        const float ent = sE[0] + sE[1] + sE[2] + sE[3];
        float off_loss = 0.f;
        #pragma unroll
        for (int i = 0; i < B; ++i) off_loss += sRatio[i];
        out[0] = ent / (float)((size_t)B * HW) + off_loss / (float)B;
    }
}

extern "C" void kernel_launch(void* const* d_in, const int* in_sizes, int n_in,
                              void* d_out, int out_size, void* d_ws, size_t ws_size,
                              hipStream_t stream) {
    const float* conf = (const float*)d_in[0];
    const float* off  = (const float*)d_in[1];
    const int*   inst = (const int*)d_in[2];
    const float* gto  = (const float*)d_in[3];
    float* out = (float*)d_out;
    float* ws  = (float*)d_ws;

    coloss_reduce<<<dim3(NBLK), dim3(THREADS), 0, stream>>>(conf, off, inst, gto, ws);
    coloss_finalize<<<1, 256, 0, stream>>>(ws, out);
}

// Round 7
// 27.075 us; speedup vs baseline: 1.0424x; 1.0424x over previous
//
#include <hip/hip_runtime.h>
#include <hip/hip_bf16.h>

// Problem constants (from the reference)
constexpr int B = 16, C = 2, H = 512, W = 512;
constexpr int HW = H * W;                    // 262144 pixels per batch
constexpr int BLOCKS_PER_BATCH = 64;         // 4096 pixels per block
constexpr int NBLK = B * BLOCKS_PER_BATCH;   // 1024 blocks
constexpr int THREADS = 256;                 // 16 px/thread = 4 float4 groups per stream
constexpr int GROUPS = 4;                    // float4 groups per thread
constexpr int VEC_PER_BLOCK = (HW / BLOCKS_PER_BATCH) / 4;   // 1024 float4 groups
constexpr float BG_WEIGHT = 0.4f;

struct Frag {
    float4 c0, c1, o0, o1, g0, g1;
    int4   iv;
};

__device__ __forceinline__ Frag loadFrag(const float* __restrict__ conf0,
                                         const float* __restrict__ conf1,
                                         const float* __restrict__ off0,
                                         const float* __restrict__ off1,
                                         const float* __restrict__ gt0,
                                         const float* __restrict__ gt1,
                                         const int*   __restrict__ ins,
                                         int p) {
    Frag f;
    f.c0 = ((const float4*)conf0)[p];
    f.c1 = ((const float4*)conf1)[p];
    f.o0 = ((const float4*)off0)[p];
    f.o1 = ((const float4*)off1)[p];
    f.g0 = ((const float4*)gt0)[p];
    f.g1 = ((const float4*)gt1)[p];
    f.iv = ((const int4*)ins)[p];
    return f;
}

// Workspace layout (floats):
//   ws[0      .. NBLK)    per-block entropy partial
//   ws[NBLK   .. 2*NBLK)  per-block fg squared-error partial
//   ws[2*NBLK .. 3*NBLK)  per-block fg count partial
// Every slot is unconditionally written each launch -> no zeroing needed.
__global__ __launch_bounds__(THREADS) void coloss_reduce(
    const float* __restrict__ conf,   // [B,2,H,W]
    const float* __restrict__ off,    // [B,2,H,W]
    const int*   __restrict__ inst,   // [B,1,H,W]
    const float* __restrict__ gto,    // [B,2,H,W]
    float* __restrict__ ws)
{
    const int b   = blockIdx.x / BLOCKS_PER_BATCH;
    const int blk = blockIdx.x % BLOCKS_PER_BATCH;

    const float* conf0 = conf + (size_t)b * C * HW;
    const float* conf1 = conf0 + HW;
    const float* off0  = off  + (size_t)b * 2 * HW;
    const float* off1  = off0 + HW;
    const float* gt0   = gto  + (size_t)b * 2 * HW;
    const float* gt1   = gt0 + HW;
    const int*   ins   = inst + (size_t)b * HW;

    const int p0 = blk * VEC_PER_BLOCK + (int)threadIdx.x;

    // ---- issue ALL 28 loads (4 fragments x 7 streams) before any compute ----
    const Frag fA = loadFrag(conf0, conf1, off0, off1, gt0, gt1, ins, p0);
    const Frag fB = loadFrag(conf0, conf1, off0, off1, gt0, gt1, ins, p0 + THREADS);
    const Frag fC = loadFrag(conf0, conf1, off0, off1, gt0, gt1, ins, p0 + 2 * THREADS);
    const Frag fD = loadFrag(conf0, conf1, off0, off1, gt0, gt1, ins, p0 + 3 * THREADS);

    float entAcc = 0.f;
    float sqAcc  = 0.f;
    float fcnt   = 0.f;

    auto accum = [&](float cc0, float cc1, float oo0, float oo1,
                     float gg0, float gg1, int ii) {
        const bool fg = (ii != 0);
        const float gathered = fg ? cc1 : cc0;
        float e = -__logf(gathered);
        e *= fg ? 1.0f : BG_WEIGHT;
        entAcc += e;
        const float d0 = gg0 - oo0;
        const float d1 = gg1 - oo1;
        const float t  = d0 * d0 + d1 * d1;
        if (fg) { sqAcc += t; fcnt += 1.0f; }
    };

    auto accumFrag = [&](const Frag& f) {
        accum(f.c0.x, f.c1.x, f.o0.x, f.o1.x, f.g0.x, f.g1.x, f.iv.x);
        accum(f.c0.y, f.c1.y, f.o0.y, f.o1.y, f.g0.y, f.g1.y, f.iv.y);
        accum(f.c0.z, f.c1.z, f.o0.z, f.o1.z, f.g0.z, f.g1.z, f.iv.z);
        accum(f.c0.w, f.c1.w, f.o0.w, f.o1.w, f.g0.w, f.g1.w, f.iv.w);
    };

    accumFrag(fA);
    accumFrag(fB);
    accumFrag(fC);
    accumFrag(fD);

    // wave (64-lane) butterfly reduce
    #pragma unroll
    for (int m = 32; m >= 1; m >>= 1) {
        entAcc += __shfl_xor(entAcc, m, 64);
        sqAcc  += __shfl_xor(sqAcc,  m, 64);
        fcnt   += __shfl_xor(fcnt,   m, 64);
    }

    __shared__ float sEnt[4], sSq[4], sCnt[4];
    const int wave = threadIdx.x >> 6;
    const int lane = threadIdx.x & 63;
    if (lane == 0) { sEnt[wave] = entAcc; sSq[wave] = sqAcc; sCnt[wave] = fcnt; }
    __syncthreads();

    if (threadIdx.x == 0) {
        const int g = blockIdx.x;
        ws[g]            = sEnt[0] + sEnt[1] + sEnt[2] + sEnt[3];
        ws[NBLK + g]     = sSq[0]  + sSq[1]  + sSq[2]  + sSq[3];
        ws[2 * NBLK + g] = sCnt[0] + sCnt[1] + sCnt[2] + sCnt[3];
    }
}

__global__ __launch_bounds__(256) void coloss_finalize(const float* __restrict__ ws,
                                                       float* __restrict__ out)
{
    const float* entp = ws;
    const float* sqp  = ws + NBLK;
    const float* cntp = ws + 2 * NBLK;

    // --- entropy: sum all NBLK partials across the block ---
    float e = 0.f;
    for (int i = threadIdx.x; i < NBLK; i += 256) e += entp[i];

    // --- per-batch sq/cnt: 16 threads per batch ---
    const int b = threadIdx.x >> 4;       // 0..15
    const int t = threadIdx.x & 15;       // 0..15
    float s = 0.f, c = 0.f;
    for (int i = t; i < BLOCKS_PER_BATCH; i += 16) {
        s += sqp[b * BLOCKS_PER_BATCH + i];
        c += cntp[b * BLOCKS_PER_BATCH + i];
    }
    #pragma unroll
    for (int m = 8; m >= 1; m >>= 1) {    // reduce within 16-lane subgroup
        s += __shfl_xor(s, m, 64);
        c += __shfl_xor(c, m, 64);
    }
    __shared__ float sRatio[16];
    if (t == 0) sRatio[b] = (c > 0.f) ? (s / c) : 0.f;

    // entropy wave reduce + cross-wave via LDS
    #pragma unroll
    for (int m = 32; m >= 1; m >>= 1) e += __shfl_xor(e, m, 64);
    __shared__ float sE[4];
    if ((threadIdx.x & 63) == 0) sE[threadIdx.x >> 6] = e;
    __syncthreads();

    if (threadIdx.x == 0) {
        const float ent = sE[0] + sE[1] + sE[2] + sE[3];
        float off_loss = 0.f;
        #pragma unroll
        for (int i = 0; i < B; ++i) off_loss += sRatio[i];
        out[0] = ent / (float)((size_t)B * HW) + off_loss / (float)B;
    }
}

extern "C" void kernel_launch(void* const* d_in, const int* in_sizes, int n_in,
                              void* d_out, int out_size, void* d_ws, size_t ws_size,
                              hipStream_t stream) {
    const float* conf = (const float*)d_in[0];
    const float* off  = (const float*)d_in[1];
    const int*   inst = (const int*)d_in[2];
    const float* gto  = (const float*)d_in[3];
    float* out = (float*)d_out;
    float* ws  = (float*)d_ws;

    coloss_reduce<<<dim3(NBLK), dim3(THREADS), 0, stream>>>(conf, off, inst, gto, ws);
    coloss_finalize<<<1, 256, 0, stream>>>(ws, out);
}

// Round 8
// 26.714 us; speedup vs baseline: 1.0564x; 1.0135x over previous
//
#include <hip/hip_runtime.h>
#include <hip/hip_bf16.h>

// Problem constants (from the reference)
constexpr int B = 16, C = 2, H = 512, W = 512;
constexpr int HW = H * W;                    // 262144 pixels per batch
constexpr int BLOCKS_PER_BATCH = 64;         // 4096 pixels per block
constexpr int NBLK = B * BLOCKS_PER_BATCH;   // 1024 blocks
constexpr int THREADS = 256;                 // 16 px/thread, as 2 iters x (2 x 4px batches)
constexpr int VEC_PER_BLOCK = (HW / BLOCKS_PER_BATCH) / 4;   // 1024 float4 groups
constexpr int ITERS = VEC_PER_BLOCK / (2 * THREADS);         // 2 iterations of 2 groups
constexpr float BG_WEIGHT = 0.4f;

// Workspace layout (floats):
//   ws[0      .. NBLK)    per-block entropy partial
//   ws[NBLK   .. 2*NBLK)  per-block fg squared-error partial
//   ws[2*NBLK .. 3*NBLK)  per-block fg count partial
// Every slot is unconditionally written each launch -> no zeroing needed.
__global__ __launch_bounds__(THREADS) void coloss_reduce(
    const float* __restrict__ conf,   // [B,2,H,W]
    const float* __restrict__ off,    // [B,2,H,W]
    const int*   __restrict__ inst,   // [B,1,H,W]
    const float* __restrict__ gto,    // [B,2,H,W]
    float* __restrict__ ws)
{
    const int b   = blockIdx.x / BLOCKS_PER_BATCH;
    const int blk = blockIdx.x % BLOCKS_PER_BATCH;

    const float* conf0 = conf + (size_t)b * C * HW;
    const float* conf1 = conf0 + HW;
    const float* off0  = off  + (size_t)b * 2 * HW;
    const float* off1  = off0 + HW;
    const float* gt0   = gto  + (size_t)b * 2 * HW;
    const float* gt1   = gt0 + HW;
    const int*   ins   = inst + (size_t)b * HW;

    const int base = blk * VEC_PER_BLOCK;     // float4 index of this block's chunk

    float entAcc = 0.f;
    float sqAcc  = 0.f;
    float fcnt   = 0.f;

    auto accum = [&](float cc0, float cc1, float oo0, float oo1,
                     float gg0, float gg1, int ii) {
        const bool fg = (ii != 0);
        const float gathered = fg ? cc1 : cc0;
        float e = -__logf(gathered);
        e *= fg ? 1.0f : BG_WEIGHT;
        entAcc += e;
        const float d0 = gg0 - oo0;
        const float d1 = gg1 - oo1;
        const float t  = d0 * d0 + d1 * d1;
        if (fg) { sqAcc += t; fcnt += 1.0f; }
    };

    #pragma unroll 2
    for (int it = 0; it < ITERS; ++it) {
        const int pA = base + it * (2 * THREADS) + threadIdx.x;
        const int pB = pA + THREADS;

        // issue all 14 loads of this iteration before any compute
        const float4 c0A = ((const float4*)conf0)[pA];
        const float4 c1A = ((const float4*)conf1)[pA];
        const float4 o0A = ((const float4*)off0)[pA];
        const float4 o1A = ((const float4*)off1)[pA];
        const float4 g0A = ((const float4*)gt0)[pA];
        const float4 g1A = ((const float4*)gt1)[pA];
        const int4   ivA = ((const int4*)ins)[pA];
        const float4 c0B = ((const float4*)conf0)[pB];
        const float4 c1B = ((const float4*)conf1)[pB];
        const float4 o0B = ((const float4*)off0)[pB];
        const float4 o1B = ((const float4*)off1)[pB];
        const float4 g0B = ((const float4*)gt0)[pB];
        const float4 g1B = ((const float4*)gt1)[pB];
        const int4   ivB = ((const int4*)ins)[pB];

        accum(c0A.x, c1A.x, o0A.x, o1A.x, g0A.x, g1A.x, ivA.x);
        accum(c0A.y, c1A.y, o0A.y, o1A.y, g0A.y, g1A.y, ivA.y);
        accum(c0A.z, c1A.z, o0A.z, o1A.z, g0A.z, g1A.z, ivA.z);
        accum(c0A.w, c1A.w, o0A.w, o1A.w, g0A.w, g1A.w, ivA.w);
        accum(c0B.x, c1B.x, o0B.x, o1B.x, g0B.x, g1B.x, ivB.x);
        accum(c0B.y, c1B.y, o0B.y, o1B.y, g0B.y, g1B.y, ivB.y);
        accum(c0B.z, c1B.z, o0B.z, o1B.z, g0B.z, g1B.z, ivB.z);
        accum(c0B.w, c1B.w, o0B.w, o1B.w, g0B.w, g1B.w, ivB.w);
    }

    // wave (64-lane) butterfly reduce
    #pragma unroll
    for (int m = 32; m >= 1; m >>= 1) {
        entAcc += __shfl_xor(entAcc, m, 64);
        sqAcc  += __shfl_xor(sqAcc,  m, 64);
        fcnt   += __shfl_xor(fcnt,   m, 64);
    }

    __shared__ float sEnt[4], sSq[4], sCnt[4];
    const int wave = threadIdx.x >> 6;
    const int lane = threadIdx.x & 63;
    if (lane == 0) { sEnt[wave] = entAcc; sSq[wave] = sqAcc; sCnt[wave] = fcnt; }
    __syncthreads();

    if (threadIdx.x == 0) {
        const int g = blockIdx.x;
        ws[g]            = sEnt[0] + sEnt[1] + sEnt[2] + sEnt[3];
        ws[NBLK + g]     = sSq[0]  + sSq[1]  + sSq[2]  + sSq[3];
        ws[2 * NBLK + g] = sCnt[0] + sCnt[1] + sCnt[2] + sCnt[3];
    }
}

__global__ __launch_bounds__(256) void coloss_finalize(const float* __restrict__ ws,
                                                       float* __restrict__ out)
{
    const float* entp = ws;
    const float* sqp  = ws + NBLK;
    const float* cntp = ws + 2 * NBLK;

    // --- entropy: sum all NBLK partials across the block ---
    float e = 0.f;
    for (int i = threadIdx.x; i < NBLK; i += 256) e += entp[i];

    // --- per-batch sq/cnt: 16 threads per batch ---
    const int b = threadIdx.x >> 4;       // 0..15
    const int t = threadIdx.x & 15;       // 0..15
    float s = 0.f, c = 0.f;
    for (int i = t; i < BLOCKS_PER_BATCH; i += 16) {
        s += sqp[b * BLOCKS_PER_BATCH + i];
        c += cntp[b * BLOCKS_PER_BATCH + i];
    }
    #pragma unroll
    for (int m = 8; m >= 1; m >>= 1) {    // reduce within 16-lane subgroup
        s += __shfl_xor(s, m, 64);
        c += __shfl_xor(c, m, 64);
    }
    __shared__ float sRatio[16];
    if (t == 0) sRatio[b] = (c > 0.f) ? (s / c) : 0.f;

    // entropy wave reduce + cross-wave via LDS
    #pragma unroll
    for (int m = 32; m >= 1; m >>= 1) e += __shfl_xor(e, m, 64);
    __shared__ float sE[4];
    if ((threadIdx.x & 63) == 0) sE[threadIdx.x >> 6] = e;
    __syncthreads();

    if (threadIdx.x == 0) {
        const float ent = sE[0] + sE[1] + sE[2] + sE[3];
        float off_loss = 0.f;
        #pragma unroll
        for (int i = 0; i < B; ++i) off_loss += sRatio[i];
        out[0] = ent / (float)((size_t)B * HW) + off_loss / (float)B;
    }
}

extern "C" void kernel_launch(void* const* d_in, const int* in_sizes, int n_in,
                              void* d_out, int out_size, void* d_ws, size_t ws_size,
                              hipStream_t stream) {
    const float* conf = (const float*)d_in[0];
    const float* off  = (const float*)d_in[1];
    const int*   inst = (const int*)d_in[2];
    const float* gto  = (const float*)d_in[3];
    float* out = (float*)d_out;
    float* ws  = (float*)d_ws;

    coloss_reduce<<<dim3(NBLK), dim3(THREADS), 0, stream>>>(conf, off, inst, gto, ws);
    coloss_finalize<<<1, 256, 0, stream>>>(ws, out);
}